// Round 1
// 1024.848 us; speedup vs baseline: 1.0927x; 1.0927x over previous
//
#include <hip/hip_runtime.h>
#include <math.h>

// Problem constants (fixed by setup_inputs)
#define Bz 8
#define Tz 1024
#define Dz 512
#define FFz 2048
#define Hz 8
#define DHz 64
#define Mz (Bz * Tz)  // 8192 rows

typedef __attribute__((ext_vector_type(8))) short short8;   // 8 bf16 (4 VGPRs)
typedef __attribute__((ext_vector_type(4))) float f32x4;    // MFMA accumulator

__device__ inline unsigned short f2bf(float f) {  // RNE fp32 -> bf16
  unsigned u = __builtin_bit_cast(unsigned, f);
  return (unsigned short)((u + 0x7FFFu + ((u >> 16) & 1u)) >> 16);
}
__device__ inline float bf2f(unsigned short h) {
  unsigned u = (unsigned)h << 16;
  return __builtin_bit_cast(float, u);
}

// ---------------------------------------------------------------------------
// Fused prep: 10 weight convert+transposes (fp32 [K,N] -> bf16 [N,K]) +
// colsum zero-fill + x -> bf16.
// ---------------------------------------------------------------------------
struct WDesc { const float* src; unsigned short* dst; int K; int N; int blk0; };
struct PrepArgs { WDesc d[10]; int nwc; };

__global__ __launch_bounds__(256) void prep_kernel(PrepArgs P,
    const float* __restrict__ x, unsigned short* __restrict__ xbf,
    float* __restrict__ csz)
{
  const int bid = blockIdx.x;
  const int tid = threadIdx.x;
  if (bid < P.nwc) {  // wconv slice
    int i = 0;
    while (i < 9 && bid >= P.d[i + 1].blk0) ++i;
    const WDesc w = P.d[i];
    const int lb = bid - w.blk0;
    const int nbn = w.N / 32;
    const int bn = (lb % nbn) * 32, bk = (lb / nbn) * 32;
    __shared__ float t[32][33];
    const int tx = tid & 31, ty = tid >> 5;
#pragma unroll
    for (int r = 0; r < 32; r += 8)
      t[ty + r][tx] = w.src[(size_t)(bk + ty + r) * w.N + bn + tx];
    __syncthreads();
#pragma unroll
    for (int r = 0; r < 32; r += 8)
      w.dst[(size_t)(bn + ty + r) * w.K + bk + tx] = f2bf(t[tx][ty + r]);
  } else if (bid < P.nwc + 64) {  // zero slice (CS1+CS2 = 16384 floats)
    int idx = (bid - P.nwc) * 256 + tid;
    csz[idx] = 0.f;
  } else {  // fconv slice: 4096 blocks, 4 floats/thread
    int i = (bid - P.nwc - 64) * 256 + tid;
    float4 v = *reinterpret_cast<const float4*>(&x[(size_t)i * 4]);
    ushort4 o;
    o.x = f2bf(v.x); o.y = f2bf(v.y); o.z = f2bf(v.z); o.w = f2bf(v.w);
    *reinterpret_cast<ushort4*>(&xbf[(size_t)i * 4]) = o;
  }
}

// ---------------------------------------------------------------------------
// bf16 MFMA GEMM, 64x64 tile per wave, direct-from-global fragments.
// Epilogue modes: 0 fp32 C | 1 bf16 C | 2 bf16 C + ReLU
//   | 4 V^T layout: p1[((b*H+h)*64+d)*T + t] bf16 (N must be 512)
//   | 5 merged QKV (N=1536): cols 0-511 -> p1 bf16, 512-1023 -> p2,
//     1024-1535 -> p3 in V^T layout.
// ---------------------------------------------------------------------------
__global__ __launch_bounds__(64) void mfma_gemm_kernel(
    const unsigned short* __restrict__ A, const unsigned short* __restrict__ BT,
    void* __restrict__ p1, void* __restrict__ p2, void* __restrict__ p3,
    int K, int N, int mode)
{
  const int l = threadIdx.x;
  const int m0 = blockIdx.y * 64;
  const int n0 = blockIdx.x * 64;
  const int mr = l & 15, quad = l >> 4;

  f32x4 acc[4][4];
  const f32x4 zero = {0.f, 0.f, 0.f, 0.f};
#pragma unroll
  for (int i = 0; i < 4; ++i)
#pragma unroll
    for (int j = 0; j < 4; ++j) acc[i][j] = zero;

  const unsigned short* Ap = A + (size_t)(m0 + mr) * K + quad * 8;
  const unsigned short* Bp = BT + (size_t)(n0 + mr) * K + quad * 8;

  short8 a[4], b[4], an[4], bn[4];
#pragma unroll
  for (int i = 0; i < 4; ++i) {
    a[i] = *reinterpret_cast<const short8*>(Ap + (size_t)i * 16 * K);
    b[i] = *reinterpret_cast<const short8*>(Bp + (size_t)i * 16 * K);
  }
  for (int k0 = 0; k0 < K; k0 += 32) {
    if (k0 + 32 < K) {
#pragma unroll
      for (int i = 0; i < 4; ++i) {
        an[i] = *reinterpret_cast<const short8*>(Ap + (size_t)i * 16 * K + k0 + 32);
        bn[i] = *reinterpret_cast<const short8*>(Bp + (size_t)i * 16 * K + k0 + 32);
      }
    }
#pragma unroll
    for (int i = 0; i < 4; ++i)
#pragma unroll
      for (int j = 0; j < 4; ++j)
        acc[i][j] = __builtin_amdgcn_mfma_f32_16x16x32_bf16(a[i], b[j], acc[i][j], 0, 0, 0);
#pragma unroll
    for (int i = 0; i < 4; ++i) { a[i] = an[i]; b[i] = bn[i]; }
  }

  // C/D layout: col = lane&15, row = quad*4 + reg   [measured: m89/m91]
  int emode = mode;
  unsigned short* Cbf = (unsigned short*)p1;
  unsigned short* Vt  = (unsigned short*)p1;
  int ncol = N, coff = 0;
  if (mode == 5) {  // uniform per block: n0 is a multiple of 64
    if (n0 < 512)       { emode = 1; Cbf = (unsigned short*)p1; ncol = 512; coff = 0; }
    else if (n0 < 1024) { emode = 1; Cbf = (unsigned short*)p2; ncol = 512; coff = 512; }
    else                { emode = 4; Vt = (unsigned short*)p3; coff = 1024; }
  }
  if (emode == 4) {  // V^T: 4 consecutive tokens same feature -> ushort4
#pragma unroll
    for (int i = 0; i < 4; ++i)
#pragma unroll
      for (int j = 0; j < 4; ++j) {
        const int col = n0 - coff + j * 16 + mr;  // feature: h = col>>6, d = col&63
        const int row0 = m0 + i * 16 + quad * 4;  // token base (4 consecutive)
        const int bb = row0 >> 10, t0 = row0 & 1023;
        ushort4 pk;
        pk.x = f2bf(acc[i][j][0]); pk.y = f2bf(acc[i][j][1]);
        pk.z = f2bf(acc[i][j][2]); pk.w = f2bf(acc[i][j][3]);
        *reinterpret_cast<ushort4*>(
            &Vt[((size_t)((bb * Hz + (col >> 6)) * DHz + (col & 63))) * Tz + t0]) = pk;
      }
  } else if (emode == 0) {
    float* Cf = (float*)p1;
#pragma unroll
    for (int i = 0; i < 4; ++i)
#pragma unroll
      for (int j = 0; j < 4; ++j) {
        const int col = n0 + j * 16 + mr;
#pragma unroll
        for (int rr = 0; rr < 4; ++rr)
          Cf[(size_t)(m0 + i * 16 + quad * 4 + rr) * N + col] = acc[i][j][rr];
      }
  } else {
    const bool relu = (emode == 2);
#pragma unroll
    for (int i = 0; i < 4; ++i)
#pragma unroll
      for (int j = 0; j < 4; ++j) {
        const int col = n0 - coff + j * 16 + mr;
#pragma unroll
        for (int rr = 0; rr < 4; ++rr) {
          float v = acc[i][j][rr];
          if (relu) v = fmaxf(v, 0.f);
          Cbf[(size_t)(m0 + i * 16 + quad * 4 + rr) * ncol + col] = f2bf(v);
        }
      }
  }
}

// ---------------------------------------------------------------------------
// fp32 VALU GEMM for layer-1 Q AND K in one dispatch. Epilogue emits
// compensated bf16 hi/lo pairs: hi = bf16(v) (bit-identical to previous
// QHbf/KHbf), lo = bf16(v - hi). hi+lo carries ~17 mantissa bits, enabling
// bf16x3 MFMA reconstruction of fp32-accurate Q.K^T for the mask path.
// ---------------------------------------------------------------------------
__global__ __launch_bounds__(256) void gemm_qk_kernel(
    const float* __restrict__ A, const float* __restrict__ vqkv,
    unsigned short* __restrict__ Qhi, unsigned short* __restrict__ Qlo,
    unsigned short* __restrict__ Khi, unsigned short* __restrict__ Klo,
    int N, int K)
{
  __shared__ float As[16][132];
  __shared__ float Bs[16][132];
  const int tid = threadIdx.x;
  const int sel = blockIdx.y >> 6;
  const int bm = (blockIdx.y & 63) * 128;
  const int bn = blockIdx.x * 128;
  const float* Bm = vqkv + (size_t)sel * Dz * Dz;
  unsigned short* Chi = sel ? Khi : Qhi;
  unsigned short* Clo = sel ? Klo : Qlo;
  const int tx = tid & 15, ty = tid >> 4;
  float acc[8][8];
#pragma unroll
  for (int i = 0; i < 8; ++i)
#pragma unroll
    for (int j = 0; j < 8; ++j) acc[i][j] = 0.f;

  for (int k0 = 0; k0 < K; k0 += 16) {
#pragma unroll
    for (int i = 0; i < 2; ++i) {
      int idx = tid + i * 256;
      int r = idx >> 2, kv = (idx & 3) << 2;
      float4 a = *reinterpret_cast<const float4*>(&A[(size_t)(bm + r) * K + k0 + kv]);
      As[kv + 0][r] = a.x; As[kv + 1][r] = a.y; As[kv + 2][r] = a.z; As[kv + 3][r] = a.w;
      int kk = idx >> 5, nv = (idx & 31) << 2;
      *reinterpret_cast<float4*>(&Bs[kk][nv]) =
          *reinterpret_cast<const float4*>(&Bm[(size_t)(k0 + kk) * N + bn + nv]);
    }
    __syncthreads();
#pragma unroll
    for (int kk = 0; kk < 16; ++kk) {
      float ar[8], br[8];
#pragma unroll
      for (int i = 0; i < 8; ++i) ar[i] = As[kk][ty * 8 + i];
#pragma unroll
      for (int j = 0; j < 4; ++j) {
        br[j]     = Bs[kk][tx * 4 + j];
        br[4 + j] = Bs[kk][64 + tx * 4 + j];
      }
#pragma unroll
      for (int i = 0; i < 8; ++i)
#pragma unroll
        for (int j = 0; j < 8; ++j) acc[i][j] += ar[i] * br[j];
    }
    __syncthreads();
  }
#pragma unroll
  for (int i = 0; i < 8; ++i) {
    size_t row = (size_t)(bm + ty * 8 + i);
    ushort4 h0, h1, l0, l1;
#pragma unroll
    for (int j = 0; j < 4; ++j) {
      float v0 = acc[i][j], v1 = acc[i][4 + j];
      unsigned short a0 = f2bf(v0); float r0 = v0 - bf2f(a0);  // exact residual
      unsigned short a1 = f2bf(v1); float r1 = v1 - bf2f(a1);
      reinterpret_cast<unsigned short*>(&h0)[j] = a0;
      reinterpret_cast<unsigned short*>(&l0)[j] = f2bf(r0);
      reinterpret_cast<unsigned short*>(&h1)[j] = a1;
      reinterpret_cast<unsigned short*>(&l1)[j] = f2bf(r1);
    }
    *reinterpret_cast<ushort4*>(&Chi[row * N + bn + tx * 4]) = h0;
    *reinterpret_cast<ushort4*>(&Chi[row * N + bn + 64 + tx * 4]) = h1;
    *reinterpret_cast<ushort4*>(&Clo[row * N + bn + tx * 4]) = l0;
    *reinterpret_cast<ushort4*>(&Clo[row * N + bn + 64 + tx * 4]) = l1;
  }
}

// ---------------------------------------------------------------------------
// Layer-1 z pass via bf16x3 MFMA: S = Qh.Kh + Qh.Kl + Ql.Kh (fp32 accum,
// ~2^-17 relative error vs fp32 GEMM). Deterministic shuffle reduction.
// ---------------------------------------------------------------------------
__global__ __launch_bounds__(256) void attn_z_kernel(
    const unsigned short* __restrict__ Qh, const unsigned short* __restrict__ Ql,
    const unsigned short* __restrict__ Kh, const unsigned short* __restrict__ Kl,
    float* __restrict__ invzG)
{
  const int tid = threadIdx.x;
  const int lane = tid & 63, wave = tid >> 6;
  const int c = lane & 15, quad = lane >> 4;
  const int qt = blockIdx.x & 15;
  const int h  = (blockIdx.x >> 4) & 7;
  const int b  = blockIdx.x >> 7;
  const size_t bT = (size_t)b * Tz;
  const int qrow = qt * 64 + wave * 16;
  const int hoff = h * DHz;

  const size_t qbase = (bT + qrow + c) * Dz + hoff + quad * 8;
  short8 q0h = *reinterpret_cast<const short8*>(Qh + qbase);
  short8 q1h = *reinterpret_cast<const short8*>(Qh + qbase + 32);
  short8 q0l = *reinterpret_cast<const short8*>(Ql + qbase);
  short8 q1l = *reinterpret_cast<const short8*>(Ql + qbase + 32);

  const f32x4 zf = {0.f, 0.f, 0.f, 0.f};
  float z[4] = {0.f, 0.f, 0.f, 0.f};

  for (int t = 0; t < 16; ++t) {
    const int k0 = t * 64;
#pragma unroll
    for (int sub = 0; sub < 4; ++sub) {
      const size_t kb = (bT + k0 + sub * 16 + c) * Dz + hoff + quad * 8;
      short8 kh0 = *reinterpret_cast<const short8*>(Kh + kb);
      short8 kh1 = *reinterpret_cast<const short8*>(Kh + kb + 32);
      short8 kl0 = *reinterpret_cast<const short8*>(Kl + kb);
      short8 kl1 = *reinterpret_cast<const short8*>(Kl + kb + 32);
      f32x4 acc = zf;
      acc = __builtin_amdgcn_mfma_f32_16x16x32_bf16(q0h, kh0, acc, 0, 0, 0);
      acc = __builtin_amdgcn_mfma_f32_16x16x32_bf16(q1h, kh1, acc, 0, 0, 0);
      acc = __builtin_amdgcn_mfma_f32_16x16x32_bf16(q0h, kl0, acc, 0, 0, 0);
      acc = __builtin_amdgcn_mfma_f32_16x16x32_bf16(q1h, kl1, acc, 0, 0, 0);
      acc = __builtin_amdgcn_mfma_f32_16x16x32_bf16(q0l, kh0, acc, 0, 0, 0);
      acc = __builtin_amdgcn_mfma_f32_16x16x32_bf16(q1l, kh1, acc, 0, 0, 0);
#pragma unroll
      for (int rr = 0; rr < 4; ++rr) z[rr] += __expf(acc[rr] * 0.125f);
    }
  }
#pragma unroll
  for (int w = 1; w < 16; w <<= 1) {
#pragma unroll
    for (int rr = 0; rr < 4; ++rr) z[rr] += __shfl_xor(z[rr], w);
  }
  if (c == 0) {
#pragma unroll
    for (int rr = 0; rr < 4; ++rr)
      invzG[(size_t)(b * Hz + h) * Tz + qrow + quad * 4 + rr] = 1.f / z[rr];
  }
}

// ---------------------------------------------------------------------------
// Layer-1 ctx via MFMA with FUSED deterministic colsum. QK^T is bf16x3
// (mask-grade precision); P stored bf16 for PV (continuous path only).
// Colsum: per-wave single-writer CSP rows (each key visited exactly once
// per wave -> plain store, no atomics), fixed-order combine -> PART.
// ---------------------------------------------------------------------------
__global__ __launch_bounds__(256) void attn_ctx_kernel(
    const unsigned short* __restrict__ Qh, const unsigned short* __restrict__ Ql,
    const unsigned short* __restrict__ Kh, const unsigned short* __restrict__ Kl,
    const unsigned short* __restrict__ Vt, const float* __restrict__ invzG,
    unsigned short* __restrict__ ctx, float* __restrict__ part)
{
  __shared__ unsigned short Pld[64][76];
  __shared__ float CSP[4][1024];  // per-wave colsum partials (single writer)
  const int tid = threadIdx.x;
  const int lane = tid & 63, wave = tid >> 6;
  const int c = lane & 15, quad = lane >> 4;
  const int qt = blockIdx.x & 15;
  const int h  = (blockIdx.x >> 4) & 7;
  const int b  = blockIdx.x >> 7;
  const size_t bT = (size_t)b * Tz;
  const int qrow = qt * 64 + wave * 16;
  const int hoff = h * DHz;

  const size_t qbase = (bT + qrow + c) * Dz + hoff + quad * 8;
  short8 q0h = *reinterpret_cast<const short8*>(Qh + qbase);
  short8 q1h = *reinterpret_cast<const short8*>(Qh + qbase + 32);
  short8 q0l = *reinterpret_cast<const short8*>(Ql + qbase);
  short8 q1l = *reinterpret_cast<const short8*>(Ql + qbase + 32);

  float invz[4];
#pragma unroll
  for (int rr = 0; rr < 4; ++rr)
    invz[rr] = invzG[(size_t)(b * Hz + h) * Tz + qrow + quad * 4 + rr];

  const f32x4 zf = {0.f, 0.f, 0.f, 0.f};
  f32x4 ot[4] = {zf, zf, zf, zf};

  for (int t = 0; t < 16; ++t) {
    const int k0 = t * 64;
#pragma unroll
    for (int sub = 0; sub < 4; ++sub) {
      const size_t kb = (bT + k0 + sub * 16 + c) * Dz + hoff + quad * 8;
      short8 kh0 = *reinterpret_cast<const short8*>(Kh + kb);
      short8 kh1 = *reinterpret_cast<const short8*>(Kh + kb + 32);
      short8 kl0 = *reinterpret_cast<const short8*>(Kl + kb);
      short8 kl1 = *reinterpret_cast<const short8*>(Kl + kb + 32);
      f32x4 acc = zf;
      acc = __builtin_amdgcn_mfma_f32_16x16x32_bf16(q0h, kh0, acc, 0, 0, 0);
      acc = __builtin_amdgcn_mfma_f32_16x16x32_bf16(q1h, kh1, acc, 0, 0, 0);
      acc = __builtin_amdgcn_mfma_f32_16x16x32_bf16(q0h, kl0, acc, 0, 0, 0);
      acc = __builtin_amdgcn_mfma_f32_16x16x32_bf16(q1h, kl1, acc, 0, 0, 0);
      acc = __builtin_amdgcn_mfma_f32_16x16x32_bf16(q0l, kh0, acc, 0, 0, 0);
      acc = __builtin_amdgcn_mfma_f32_16x16x32_bf16(q1l, kh1, acc, 0, 0, 0);
      float p[4];
#pragma unroll
      for (int rr = 0; rr < 4; ++rr)
        p[rr] = __expf(acc[rr] * 0.125f) * invz[rr];
      float cs = p[0] + p[1] + p[2] + p[3];
      cs += __shfl_xor(cs, 16);
      cs += __shfl_xor(cs, 32);
      if (quad == 0) CSP[wave][k0 + sub * 16 + c] = cs;  // key visited once
#pragma unroll
      for (int rr = 0; rr < 4; ++rr)
        Pld[(wave << 4) + quad * 4 + rr][sub * 16 + c] = f2bf(p[rr]);
    }
    union { short8 v; ushort4 hh[2]; } pb0, pb1;
    pb0.hh[0] = *reinterpret_cast<const ushort4*>(&Pld[(wave << 4) + c][quad * 8]);
    pb0.hh[1] = *reinterpret_cast<const ushort4*>(&Pld[(wave << 4) + c][quad * 8 + 4]);
    pb1.hh[0] = *reinterpret_cast<const ushort4*>(&Pld[(wave << 4) + c][32 + quad * 8]);
    pb1.hh[1] = *reinterpret_cast<const ushort4*>(&Pld[(wave << 4) + c][32 + quad * 8 + 4]);
#pragma unroll
    for (int ds = 0; ds < 4; ++ds) {
      const size_t va = ((size_t)((b * Hz + h) * DHz + ds * 16 + c)) * Tz + k0 + quad * 8;
      short8 v0 = *reinterpret_cast<const short8*>(Vt + va);
      short8 v1 = *reinterpret_cast<const short8*>(Vt + va + 32);
      ot[ds] = __builtin_amdgcn_mfma_f32_16x16x32_bf16(v0, pb0.v, ot[ds], 0, 0, 0);
      ot[ds] = __builtin_amdgcn_mfma_f32_16x16x32_bf16(v1, pb1.v, ot[ds], 0, 0, 0);
    }
  }

  const size_t cb = (bT + qrow + c) * Dz + hoff;
#pragma unroll
  for (int ds = 0; ds < 4; ++ds) {
    ushort4 pk;
    pk.x = f2bf(ot[ds][0]); pk.y = f2bf(ot[ds][1]);
    pk.z = f2bf(ot[ds][2]); pk.w = f2bf(ot[ds][3]);
    *reinterpret_cast<ushort4*>(&ctx[cb + ds * 16 + quad * 4]) = pk;
  }
  __syncthreads();
  // fixed-order combine + non-atomic block-partial write (deterministic)
  for (int i = tid; i < 1024; i += 256) {
    float v = ((CSP[0][i] + CSP[1][i]) + CSP[2][i]) + CSP[3][i];
    part[(size_t)blockIdx.x * 1024 + i] = v * (1.f / Hz);
  }
}

// ---------------------------------------------------------------------------
// Deterministic colsum reduce: CS1[b,key] = sum over the 128 (h,qt) block
// partials in fixed ascending order. One thread per output.
// ---------------------------------------------------------------------------
__global__ __launch_bounds__(256) void colsum_reduce_kernel(
    const float* __restrict__ part, float* __restrict__ colsum)
{
  const int i = blockIdx.x * 256 + threadIdx.x;  // 0..8191
  const int b = i >> 10, k = i & 1023;
  const float* p = part + (size_t)(b * 128) * 1024 + k;
  float s = 0.f;
  for (int j = 0; j < 128; ++j) s += p[(size_t)j * 1024];
  colsum[i] = s;
}

// ---------------------------------------------------------------------------
// Layer-2 MFMA attention (masked), with k-tile range skipping. CS2 feeds only
// the continuous wl softmax -> atomics are fine here.
// ---------------------------------------------------------------------------
__global__ __launch_bounds__(256) void attn_mfma2_kernel(
    const unsigned short* __restrict__ Qh, const unsigned short* __restrict__ Kh,
    const unsigned short* __restrict__ Vt, const int* __restrict__ ids,
    const int* __restrict__ wst,
    unsigned short* __restrict__ ctx, float* __restrict__ colsum)
{
  __shared__ unsigned short Pld[64][76];
  __shared__ float csb[1024];

  const int tid = threadIdx.x;
  const int lane = tid & 63, wave = tid >> 6;
  const int c = lane & 15, quad = lane >> 4;
  const int qt = blockIdx.x & 15;
  const int h  = (blockIdx.x >> 4) & 7;
  const int b  = blockIdx.x >> 7;
  const size_t bT = (size_t)b * Tz;
  const int qrow = qt * 64 + wave * 16;
  const int hoff = h * DHz;

  for (int i = tid; i < 1024; i += 256) csb[i] = 0.f;

  const int id_lo = ids[bT + qt * 64];
  const int id_hi = ids[bT + qt * 64 + 63];
  const int klo = wst[b * (Tz + 1) + id_lo];
  const int khi = wst[b * (Tz + 1) + id_hi + 1];
  const int t0 = klo >> 6, t1 = (khi - 1) >> 6;

  const size_t qbase = (bT + qrow + c) * Dz + hoff + quad * 8;
  short8 q0 = *reinterpret_cast<const short8*>(Qh + qbase);
  short8 q1 = *reinterpret_cast<const short8*>(Qh + qbase + 32);

  int qid[4];
#pragma unroll
  for (int rr = 0; rr < 4; ++rr) qid[rr] = ids[bT + qrow + quad * 4 + rr];
  __syncthreads();  // csb zeros visible before pass-2 atomics

  const f32x4 zf = {0.f, 0.f, 0.f, 0.f};

  // pass 1: z
  float z[4] = {0.f, 0.f, 0.f, 0.f};
  for (int t = t0; t <= t1; ++t) {
    const int k0 = t * 64;
#pragma unroll
    for (int sub = 0; sub < 4; ++sub) {
      const size_t kb = (bT + k0 + sub * 16 + c) * Dz + hoff + quad * 8;
      short8 kh0 = *reinterpret_cast<const short8*>(Kh + kb);
      short8 kh1 = *reinterpret_cast<const short8*>(Kh + kb + 32);
      f32x4 acc = zf;
      acc = __builtin_amdgcn_mfma_f32_16x16x32_bf16(q0, kh0, acc, 0, 0, 0);
      acc = __builtin_amdgcn_mfma_f32_16x16x32_bf16(q1, kh1, acc, 0, 0, 0);
      int kidv = ids[bT + k0 + sub * 16 + c];
#pragma unroll
      for (int rr = 0; rr < 4; ++rr) {
        float e = __expf(acc[rr] * 0.125f);
        if (qid[rr] != kidv) e = 0.f;
        z[rr] += e;
      }
    }
  }
#pragma unroll
  for (int w = 1; w < 16; w <<= 1) {
#pragma unroll
    for (int rr = 0; rr < 4; ++rr) z[rr] += __shfl_xor(z[rr], w);
  }
  float invz[4];
#pragma unroll
  for (int rr = 0; rr < 4; ++rr) invz[rr] = 1.f / z[rr];

  // pass 2: P, colsum, PV
  f32x4 ot[4] = {zf, zf, zf, zf};
  for (int t = t0; t <= t1; ++t) {
    const int k0 = t * 64;
#pragma unroll
    for (int sub = 0; sub < 4; ++sub) {
      const size_t kb = (bT + k0 + sub * 16 + c) * Dz + hoff + quad * 8;
      short8 kh0 = *reinterpret_cast<const short8*>(Kh + kb);
      short8 kh1 = *reinterpret_cast<const short8*>(Kh + kb + 32);
      f32x4 acc = zf;
      acc = __builtin_amdgcn_mfma_f32_16x16x32_bf16(q0, kh0, acc, 0, 0, 0);
      acc = __builtin_amdgcn_mfma_f32_16x16x32_bf16(q1, kh1, acc, 0, 0, 0);
      int kidv = ids[bT + k0 + sub * 16 + c];
      float p[4];
#pragma unroll
      for (int rr = 0; rr < 4; ++rr) {
        float e = __expf(acc[rr] * 0.125f);
        if (qid[rr] != kidv) e = 0.f;
        p[rr] = e * invz[rr];
      }
      float cs = p[0] + p[1] + p[2] + p[3];
      cs += __shfl_xor(cs, 16);
      cs += __shfl_xor(cs, 32);
      if (quad == 0) atomicAdd(&csb[k0 + sub * 16 + c], cs);
#pragma unroll
      for (int rr = 0; rr < 4; ++rr)
        Pld[(wave << 4) + quad * 4 + rr][sub * 16 + c] = f2bf(p[rr]);
    }
    union { short8 v; ushort4 hh[2]; } pb0, pb1;
    pb0.hh[0] = *reinterpret_cast<const ushort4*>(&Pld[(wave << 4) + c][quad * 8]);
    pb0.hh[1] = *reinterpret_cast<const ushort4*>(&Pld[(wave << 4) + c][quad * 8 + 4]);
    pb1.hh[0] = *reinterpret_cast<const ushort4*>(&Pld[(wave << 4) + c][32 + quad * 8]);
    pb1.hh[1] = *reinterpret_cast<const ushort4*>(&Pld[(wave << 4) + c][32 + quad * 8 + 4]);
#pragma unroll
    for (int ds = 0; ds < 4; ++ds) {
      const size_t va = ((size_t)((b * Hz + h) * DHz + ds * 16 + c)) * Tz + k0 + quad * 8;
      short8 v0 = *reinterpret_cast<const short8*>(Vt + va);
      short8 v1 = *reinterpret_cast<const short8*>(Vt + va + 32);
      ot[ds] = __builtin_amdgcn_mfma_f32_16x16x32_bf16(v0, pb0.v, ot[ds], 0, 0, 0);
      ot[ds] = __builtin_amdgcn_mfma_f32_16x16x32_bf16(v1, pb1.v, ot[ds], 0, 0, 0);
    }
  }

  const size_t cb = (bT + qrow + c) * Dz + hoff;
#pragma unroll
  for (int ds = 0; ds < 4; ++ds) {
    ushort4 pk;
    pk.x = f2bf(ot[ds][0]); pk.y = f2bf(ot[ds][1]);
    pk.z = f2bf(ot[ds][2]); pk.w = f2bf(ot[ds][3]);
    *reinterpret_cast<ushort4*>(&ctx[cb + ds * 16 + quad * 4]) = pk;
  }
  __syncthreads();
  for (int i = tid; i < 1024; i += 256)
    atomicAdd(&colsum[bT + i], csb[i] * (1.f / Hz));
}

// ---------------------------------------------------------------------------
// out = LayerNorm(resid + delta). resid fp32 (residf) if non-null else bf16.
// ---------------------------------------------------------------------------
__global__ __launch_bounds__(256) void ln_kernel(const float* __restrict__ residf,
    const unsigned short* __restrict__ residbf, const float* __restrict__ delta,
    float* __restrict__ outf, unsigned short* __restrict__ outbf)
{
  const size_t base = (size_t)blockIdx.x * Dz;
  const int tid = threadIdx.x;
  float r0, r1;
  if (residf) {
    r0 = residf[base + tid]; r1 = residf[base + tid + 256];
  } else {
    r0 = bf2f(residbf[base + tid]); r1 = bf2f(residbf[base + tid + 256]);
  }
  float x0 = r0 + delta[base + tid];
  float x1 = r1 + delta[base + tid + 256];
  __shared__ float red[4];
  float s = x0 + x1;
#pragma unroll
  for (int off = 32; off; off >>= 1) s += __shfl_down(s, off);
  if ((tid & 63) == 0) red[tid >> 6] = s;
  __syncthreads();
  const float mean = (red[0] + red[1] + red[2] + red[3]) * (1.f / Dz);
  __syncthreads();
  float d0 = x0 - mean, d1 = x1 - mean;
  float v = d0 * d0 + d1 * d1;
#pragma unroll
  for (int off = 32; off; off >>= 1) v += __shfl_down(v, off);
  if ((tid & 63) == 0) red[tid >> 6] = v;
  __syncthreads();
  const float var = (red[0] + red[1] + red[2] + red[3]) * (1.f / Dz);
  const float rstd = rsqrtf(var + 1e-5f);
  float y0 = d0 * rstd, y1 = d1 * rstd;
  if (outf) {
    outf[base + tid] = y0;
    outf[base + tid + 256] = y1;
  }
  outbf[base + tid] = f2bf(y0);
  outbf[base + tid + 256] = f2bf(y1);
}

// ---------------------------------------------------------------------------
// Per batch: min-max normalize colsum, threshold 0.5, run-length window scan.
// All reductions shfl/fixed-order -> deterministic.
// ---------------------------------------------------------------------------
__global__ __launch_bounds__(256) void window_ids_kernel(const float* __restrict__ cs,
    int* __restrict__ ids, int* __restrict__ wst, int* __restrict__ nwin)
{
  const int b = blockIdx.x, tid = threadIdx.x;
  __shared__ float vals[Tz];
  __shared__ unsigned char wb[Tz];
  __shared__ int sids[Tz];
  __shared__ float rmin[4], rmax[4];
  float mn = INFINITY, mx = -INFINITY;
  for (int t = tid; t < Tz; t += 256) {
    float v = cs[b * Tz + t];
    vals[t] = v;
    mn = fminf(mn, v); mx = fmaxf(mx, v);
  }
#pragma unroll
  for (int off = 32; off; off >>= 1) {
    mn = fminf(mn, __shfl_down(mn, off));
    mx = fmaxf(mx, __shfl_down(mx, off));
  }
  if ((tid & 63) == 0) { rmin[tid >> 6] = mn; rmax[tid >> 6] = mx; }
  __syncthreads();
  mn = fminf(fminf(rmin[0], rmin[1]), fminf(rmin[2], rmin[3]));
  mx = fmaxf(fmaxf(rmax[0], rmax[1]), fmaxf(rmax[2], rmax[3]));
  const float inv = 1.f / (mx - mn + 1e-8f);
  for (int t = tid; t < Tz; t += 256) wb[t] = (((vals[t] - mn) * inv) >= 0.5f) ? 1 : 0;
  __syncthreads();
  if (tid == 0) {
    int cur = wb[0], start = 0, wid = 0;
    sids[0] = 0;
    wst[b * (Tz + 1)] = 0;
    for (int t = 1; t < Tz; ++t) {
      int wt = wb[t];
      if (wt != cur) {
        cur = wt;
        if (start + 1 != t) {
          start = t;
          ++wid;
          wst[b * (Tz + 1) + wid] = t;
        }
      }
      sids[t] = wid;
    }
    nwin[b] = wid + 1;
    wst[b * (Tz + 1) + wid + 1] = Tz;
  }
  __syncthreads();
  for (int t = tid; t < Tz; t += 256) ids[b * Tz + t] = sids[t];
}

// ---------------------------------------------------------------------------
// wl[b,:] = softmax over keys of layer-2 colsum.
// ---------------------------------------------------------------------------
__global__ __launch_bounds__(256) void wl_softmax_kernel(const float* __restrict__ cs,
                                                         float* __restrict__ wl)
{
  const int b = blockIdx.x, tid = threadIdx.x;
  __shared__ float vals[Tz];
  __shared__ float red[4];
  float mx = -INFINITY;
  for (int t = tid; t < Tz; t += 256) {
    float v = cs[b * Tz + t];
    vals[t] = v;
    mx = fmaxf(mx, v);
  }
#pragma unroll
  for (int off = 32; off; off >>= 1) mx = fmaxf(mx, __shfl_down(mx, off));
  if ((tid & 63) == 0) red[tid >> 6] = mx;
  __syncthreads();
  mx = fmaxf(fmaxf(red[0], red[1]), fmaxf(red[2], red[3]));
  __syncthreads();
  float se = 0.f;
  for (int t = tid; t < Tz; t += 256) {
    float e = expf(vals[t] - mx);
    vals[t] = e;
    se += e;
  }
#pragma unroll
  for (int off = 32; off; off >>= 1) se += __shfl_down(se, off);
  if ((tid & 63) == 0) red[tid >> 6] = se;
  __syncthreads();
  const float inv = 1.f / (red[0] + red[1] + red[2] + red[3]);
  for (int t = tid; t < Tz; t += 256) wl[b * Tz + t] = vals[t] * inv;
}

// ---------------------------------------------------------------------------
// Fused outputs: word_tokens (blocks 0..8191), winmap (8192..16383),
// copy_x (16384..20479).
// ---------------------------------------------------------------------------
__global__ __launch_bounds__(256) void outputs_kernel(
    const unsigned short* __restrict__ outl, const float* __restrict__ wl,
    const int* __restrict__ wst, const int* __restrict__ nwin,
    const int* __restrict__ ids, const float* __restrict__ x,
    float* __restrict__ out, float* __restrict__ out2)
{
  const int bid = blockIdx.x;
  const int tid = threadIdx.x;
  if (bid < 8192) {  // word_tokens
    const int w = bid & (Tz - 1);
    const int b = bid >> 10;
    float a0 = 0.f, a1 = 0.f;
    if (w < nwin[b]) {
      const int s = wst[b * (Tz + 1) + w], e = wst[b * (Tz + 1) + w + 1];
      for (int t = s; t < e; ++t) {
        const float sc = wl[b * Tz + t];
        const unsigned short* p = &outl[((size_t)(b * Tz + t)) * Dz];
        a0 += bf2f(p[tid]) * sc;
        a1 += bf2f(p[tid + 256]) * sc;
      }
    }
    float* o = &out[((size_t)(b * 2 * Tz + w)) * Dz];
    o[tid] = a0;
    o[tid + 256] = a1;
  } else if (bid < 16384) {  // winmap
    const int lb = bid - 8192;
    const int w = lb & (Tz - 1);
    const int b = lb >> 10;
    const int j = tid * 4;
    int4 id4 = *reinterpret_cast<const int4*>(&ids[b * Tz + j]);
    float4 v;
    v.x = (id4.x == w) ? 1.f : 0.f;
    v.y = (id4.y == w) ? 1.f : 0.f;
    v.z = (id4.z == w) ? 1.f : 0.f;
    v.w = (id4.w == w) ? 1.f : 0.f;
    *reinterpret_cast<float4*>(&out2[((size_t)(b * Tz + w)) * Tz + j]) = v;
  } else {  // copy_x
    size_t i = (size_t)(bid - 16384) * 256 + tid;
    size_t idx = i * 4;
    size_t rowi = idx >> 9;
    size_t d = idx & 511;
    size_t b = rowi >> 10, t = rowi & 1023;
    float4 v = *reinterpret_cast<const float4*>(&x[idx]);
    *reinterpret_cast<float4*>(&out[(((b * 2 * Tz) + Tz + t) << 9) + d]) = v;
  }
}

// ---------------------------------------------------------------------------
// Orchestration: 22 dispatches. colsum_f32 replaced by bf16x3 MFMA z-pass +
// colsum fused into attn_ctx. QL/KL bf16 lo-parts live in the freed fp32
// Q/K region (recycled by PROJ/Y1 after attention, as before).
// ---------------------------------------------------------------------------
extern "C" void kernel_launch(void* const* d_in, const int* in_sizes, int n_in,
                              void* d_out, int out_size, void* d_ws, size_t ws_size,
                              hipStream_t stream)
{
  (void)in_sizes; (void)n_in; (void)out_size; (void)ws_size;
  const float* x     = (const float*)d_in[0];
  const float* vqkv  = (const float*)d_in[1];
  const float* voutw = (const float*)d_in[2];
  const float* vw1   = (const float*)d_in[3];
  const float* vw2   = (const float*)d_in[4];
  const float* lqkv  = (const float*)d_in[5];
  const float* loutw = (const float*)d_in[6];
  const float* lw1   = (const float*)d_in[7];
  const float* lw2   = (const float*)d_in[8];
  float* out = (float*)d_out;
  float* ws  = (float*)d_ws;

  unsigned short* QLbf = (unsigned short*)(ws + 0);        // bf16 Q lo (L1)
  unsigned short* KLbf = (unsigned short*)(ws + 2097152);  // bf16 K lo (L1)
  float* PROJ = ws + 0;         // written after attn_ctx (QL/KL dead)
  float* Y1   = ws + 4194304;
  unsigned short* QHbf = (unsigned short*)(ws + 8388608);   // bf16 Q hi (L1+L2)
  unsigned short* KHbf = (unsigned short*)(ws + 10485760);  // bf16 K hi (L1+L2)
  unsigned short* VT   = (unsigned short*)(ws + 12582912);
  unsigned short* SLOT1 = (unsigned short*)(ws + 14680064); // attn ctx bf16
  unsigned short* SLOT2 = (unsigned short*)(ws + 16777216); // LN bf16 out
  unsigned short* HIDbf = (unsigned short*)(ws + 18874368); // FFN hidden
  unsigned short* XBF   = (unsigned short*)(ws + 18874368); // alias (pre-FFN)
  float* PART = ws + 18874368;  // colsum block partials (1024x1024), alias:
                                // written after XBF is dead, dead before FFN1
  // bf16 transposed weights (WLQ0..2 contiguous -> merged [1536,512] matrix)
  unsigned short* WVQV = (unsigned short*)(ws + 27262976);
  unsigned short* WVO  = (unsigned short*)(ws + 27394048);
  unsigned short* WV1  = (unsigned short*)(ws + 27525120);
  unsigned short* WV2  = (unsigned short*)(ws + 28049408);
  unsigned short* WLQ0 = (unsigned short*)(ws + 28573696);
  unsigned short* WLQ1 = (unsigned short*)(ws + 28704768);
  unsigned short* WLQ2 = (unsigned short*)(ws + 28835840);
  unsigned short* WLO  = (unsigned short*)(ws + 28966912);
  unsigned short* WL1  = (unsigned short*)(ws + 29097984);
  unsigned short* WL2  = (unsigned short*)(ws + 29622272);
  // small buffers
  float* CS1   = ws + 30146560;
  float* CS2   = ws + 30154752;
  float* WLs   = ws + 30162944;
  int*   IDS   = (int*)(ws + 30171136);
  int*   WST   = (int*)(ws + 30179328);
  int*   NWIN  = (int*)(ws + 30187776);
  float* INVZ  = ws + 30195968;  // (B*H*T) = 65536 floats

  dim3 blk(256);

  // ---- fused prep: 10 wconv + zero + fconv ----
  PrepArgs P;
  auto setw = [&](int i, const float* s, unsigned short* d, int K, int N, int b0) {
    P.d[i].src = s; P.d[i].dst = d; P.d[i].K = K; P.d[i].N = N; P.d[i].blk0 = b0;
  };
  int b0 = 0;
  setw(0, vqkv + 2 * Dz * Dz, WVQV, Dz, Dz, b0); b0 += 256;
  setw(1, voutw, WVO, Dz, Dz, b0); b0 += 256;
  setw(2, vw1, WV1, Dz, FFz, b0); b0 += 1024;
  setw(3, vw2, WV2, FFz, Dz, b0); b0 += 1024;
  setw(4, lqkv + 0 * Dz * Dz, WLQ0, Dz, Dz, b0); b0 += 256;
  setw(5, lqkv + 1 * Dz * Dz, WLQ1, Dz, Dz, b0); b0 += 256;
  setw(6, lqkv + 2 * Dz * Dz, WLQ2, Dz, Dz, b0); b0 += 256;
  setw(7, loutw, WLO, Dz, Dz, b0); b0 += 256;
  setw(8, lw1, WL1, Dz, FFz, b0); b0 += 1024;
  setw(9, lw2, WL2, FFz, Dz, b0); b0 += 1024;
  P.nwc = b0;  // 5632
  prep_kernel<<<dim3(P.nwc + 64 + 4096), blk, 0, stream>>>(P, x, XBF, CS1);

  auto mgemm = [&](const unsigned short* A, const unsigned short* BT, void* p1,
                   void* p2, void* p3, int K, int N, int mode) {
    mfma_gemm_kernel<<<dim3(N / 64, Mz / 64), dim3(64), 0, stream>>>(
        A, BT, p1, p2, p3, K, N, mode);
  };

  // ---------------- layer 1 (vanilla) ----------------
  gemm_qk_kernel<<<dim3(4, 128), blk, 0, stream>>>(x, vqkv, QHbf, QLbf, KHbf, KLbf, Dz, Dz);
  mgemm(XBF, WVQV, VT, nullptr, nullptr, Dz, Dz, 4);        // V -> V^T (XBF dead after)
  attn_z_kernel<<<dim3(Bz * Hz * 16), blk, 0, stream>>>(QHbf, QLbf, KHbf, KLbf, INVZ);
  attn_ctx_kernel<<<dim3(Bz * Hz * 16), blk, 0, stream>>>(
      QHbf, QLbf, KHbf, KLbf, VT, INVZ, SLOT1, PART);
  colsum_reduce_kernel<<<dim3(32), blk, 0, stream>>>(PART, CS1);
  window_ids_kernel<<<dim3(Bz), blk, 0, stream>>>(CS1, IDS, WST, NWIN);
  mgemm(SLOT1, WVO, PROJ, nullptr, nullptr, Dz, Dz, 0);     // proj (QL/KL dead)
  ln_kernel<<<dim3(Mz), blk, 0, stream>>>(x, nullptr, PROJ, Y1, SLOT2);
  mgemm(SLOT2, WV1, HIDbf, nullptr, nullptr, Dz, FFz, 2);   // FFN1 + ReLU (PART dead)
  mgemm(HIDbf, WV2, PROJ, nullptr, nullptr, FFz, Dz, 0);    // FFN2
  ln_kernel<<<dim3(Mz), blk, 0, stream>>>(Y1, nullptr, PROJ, nullptr, SLOT2);

  // ---------------- layer 2 (block-diagonal window mask) ----------------
  mgemm(SLOT2, WLQ0, QHbf, KHbf, VT, Dz, 3 * Dz, 5);        // merged QKV
  attn_mfma2_kernel<<<dim3(Bz * Hz * 16), blk, 0, stream>>>(
      QHbf, KHbf, VT, IDS, WST, SLOT1, CS2);
  mgemm(SLOT1, WLO, PROJ, nullptr, nullptr, Dz, Dz, 0);
  ln_kernel<<<dim3(Mz), blk, 0, stream>>>(nullptr, SLOT2, PROJ, Y1, SLOT2);
  mgemm(SLOT2, WL1, HIDbf, nullptr, nullptr, Dz, FFz, 2);
  mgemm(HIDbf, WL2, PROJ, nullptr, nullptr, FFz, Dz, 0);
  ln_kernel<<<dim3(Mz), blk, 0, stream>>>(Y1, nullptr, PROJ, nullptr, SLOT2);

  // ---------------- pooling + outputs ----------------
  wl_softmax_kernel<<<dim3(Bz), blk, 0, stream>>>(CS2, WLs);
  outputs_kernel<<<dim3(20480), blk, 0, stream>>>(SLOT2, WLs, WST, NWIN, IDS, x,
                                                  out, out + (size_t)Bz * 2 * Tz * Dz);
}